// Round 12
// baseline (41.874 us; speedup 1.0000x reference)
//
#include <hip/hip_runtime.h>
#include <hip/hip_bf16.h>

#define B_ 4
#define C_ 64
#define H_ 128
#define W_ 128
#define HW_ (H_ * W_)
#define OCH_ 18

typedef __attribute__((ext_vector_type(8))) short short8;
typedef __attribute__((ext_vector_type(16))) float f32x16;
typedef __attribute__((ext_vector_type(2))) float float2v;

// ws layout (elements of unsigned short):
//   [0, W2B_ELEMS)              w2b: main weights, A-frag order (bf16)
//   [W2B_ELEMS, +W2A_ELEMS)     w2a: offset-conv weights, A-frag order (bf16)
#define W2B_ELEMS (9 * 2 * 4 * 64 * 8)   // 36864
#define W2A_ELEMS (36 * 64 * 8)          // 18432

// LDS: window 8 planes(8ch) x 6 rows x 128 cols x 16B (+pad), then per-wave offset
// exchange region: 8 waves x 18 oc x 32 px floats.
#define PSTRIDE_B (6 * 128 * 16 + 16)    // 12304
#define WIN_BYTES (8 * PSTRIDE_B)        // 98432
#define OFFL_OFS  WIN_BYTES
#define OFFW_B    (OCH_ * 32 * 4)        // 2304 per wave
#define SMEM_BYTES (WIN_BYTES + 8 * OFFW_B)   // 116864

__device__ __forceinline__ unsigned short f2bf(float f) {
  union { float f; unsigned u; } v; v.f = f;
  unsigned r = v.u + 0x7FFFu + ((v.u >> 16) & 1u);   // RNE
  return (unsigned short)(r >> 16);
}
__device__ __forceinline__ float bf2f(unsigned short h) {
  union { unsigned u; float f; } v; v.u = ((unsigned)h) << 16;
  return v.f;
}
__device__ __forceinline__ unsigned short f2bfh(float f) {   // hot path: HW cvt
  __hip_bfloat16 h = __float2bfloat16(f);
  return *reinterpret_cast<unsigned short*>(&h);
}
__device__ __forceinline__ float uaf(unsigned u) {
  union { unsigned u; float f; } v; v.u = u; return v.f;
}
// bijective XCD swizzle for 256-block grid; consecutive ho0 stay on one XCD
__device__ __forceinline__ int swz256(int x) { return (x & 7) * 32 + (x >> 3); }

// ---------------- weight pack ----------------
__global__ __launch_bounds__(256) void pack_w_only(
    const float* __restrict__ wmain, const float* __restrict__ offw,
    unsigned short* __restrict__ ws_u) {
  int idx = blockIdx.x * 256 + threadIdx.x;
  if (idx < W2B_ELEMS) {
    int i = idx & 7, lane = (idx >> 3) & 63, s = (idx >> 9) & 3;
    int mq = (idx >> 11) & 1, t = idx >> 12;
    int o = mq * 32 + (lane & 31);
    int c = 16 * s + (lane >> 5) * 8 + i;
    ws_u[idx] = f2bf(wmain[(o * 64 + c) * 9 + t]);
  } else if (idx < W2B_ELEMS + W2A_ELEMS) {
    int j = idx - W2B_ELEMS;
    int i = j & 7, lane = (j >> 3) & 63, s = j >> 9;   // s 0..35
    int kg = 16 * s + (lane >> 5) * 8 + i;
    int t = kg >> 6, c = kg & 63, oc = lane & 31;
    ws_u[idx] = (oc < OCH_) ? f2bf(offw[(oc * 64 + c) * 9 + t]) : (unsigned short)0;
  }
}

// ---------------- fused kernel v8: ROLLED loops (small code), 1 barrier ----------------
// block=(b, ho0=2*rb): 256 blocks x 512 threads (8 waves).
// wave = (r_off = wave>>2, pair = wave&3): output row ho0+r_off, px strip pair*32..+32.
__global__ __launch_bounds__(512, 2) void deform_fused8(
    const float* __restrict__ x, const float* __restrict__ bias,
    const float* __restrict__ ob, const unsigned short* __restrict__ w2b,
    const unsigned short* __restrict__ w2a, float* __restrict__ out) {
  const int blk = swz256(blockIdx.x);
  const int ho0 = (blk & 63) * 2;
  const int b   = blk >> 6;
  const int tid = threadIdx.x;
  const int lane = tid & 63;
  const int wave = tid >> 6;
  const int r_off = wave >> 2;
  const int pair  = wave & 3;
  const int ho = ho0 + r_off;
  const int pxl = lane & 31;
  const int px = pair * 32 + pxl;
  const int laneh = lane >> 5;

  __shared__ __align__(16) char smem[SMEM_BYTES];

  // ---- stage: rows ho0-2..ho0+3 (clamped), reg transpose, b128 writes ----
  const float* xb = x + (size_t)b * C_ * HW_;
  #pragma unroll
  for (int it = 0; it < 3; ++it) {
    const int u = tid + it * 512;          // 1536 units: [row(6)][p(8)][col4(32)]
    const int row  = u >> 8;
    const int p    = (u >> 5) & 7;
    const int col4 = u & 31;
    const int srow = min(H_ - 1, max(0, ho0 - 2 + row));
    const float* bp = xb + (size_t)(p * 8) * HW_ + srow * W_ + col4 * 4;
    float4 f[8];
    #pragma unroll
    for (int i = 0; i < 8; ++i) f[i] = *(const float4*)(bp + (size_t)i * HW_);
    char* outb = smem + p * PSTRIDE_B + (((row << 7) + col4 * 4) << 4);
    #pragma unroll
    for (int j = 0; j < 4; ++j) {
      short8 v;
      #pragma unroll
      for (int i = 0; i < 8; ++i)
        v[i] = (short)f2bfh(reinterpret_cast<const float*>(&f[i])[j]);
      *(short8*)(outb + j * 16) = v;
    }
  }
  __syncthreads();                         // the only barrier

  // ---- phase 1: offset conv, rolled (18 x dual-chain) ----
  f32x16 pacc_a, pacc_b;
  #pragma unroll
  for (int r = 0; r < 16; ++r) { pacc_a[r] = 0.f; pacc_b[r] = 0.f; }

  #pragma unroll 1
  for (int sq = 0; sq < 18; ++sq) {
    #pragma unroll
    for (int h = 0; h < 2; ++h) {
      const int s = 2 * sq + h;
      const int t = s >> 2;
      const int ki = (t >= 6) ? 2 : ((t >= 3) ? 1 : 0);
      const int kj = t - 3 * ki;
      const int row = ho - 1 + ki;
      const int col = px - 1 + kj;
      short8 bfr = {0, 0, 0, 0, 0, 0, 0, 0};
      if (((unsigned)row < (unsigned)H_) && ((unsigned)col < (unsigned)W_))
        bfr = *(const short8*)(smem + ((s & 3) * 2 + laneh) * PSTRIDE_B
                               + ((((ki + 1 + r_off) << 7) + col) << 4));
      const short8 afr = *(const short8*)&w2a[((size_t)s * 64 + lane) * 8];
      if (h)
        pacc_b = __builtin_amdgcn_mfma_f32_32x32x16_bf16(afr, bfr, pacc_b, 0, 0, 0);
      else
        pacc_a = __builtin_amdgcn_mfma_f32_32x32x16_bf16(afr, bfr, pacc_a, 0, 0, 0);
    }
  }

  // ---- write offsets (+bias) to wave-private LDS region; no barrier needed ----
  float* offl = (float*)(smem + OFFL_OFS + wave * OFFW_B);
  #pragma unroll
  for (int reg = 0; reg < 16; ++reg) {
    const int oc = (reg & 3) + 8 * (reg >> 2) + 4 * laneh;
    if (oc < OCH_) offl[oc * 32 + pxl] = pacc_a[reg] + pacc_b[reg] + ob[oc];
  }

  // ---- phase 2: deformable sample + einsum, rolled over 9 taps ----
  f32x16 acc0, acc1;
  #pragma unroll
  for (int r = 0; r < 16; ++r) { acc0[r] = 0.f; acc1[r] = 0.f; }

  #pragma unroll 1
  for (int t = 0; t < 9; ++t) {
    const int ki = (t >= 6) ? 2 : ((t >= 3) ? 1 : 0);
    const int kj = t - 3 * ki;
    const float dy = offl[(2 * t) * 32 + pxl];
    const float dx = offl[(2 * t + 1) * 32 + pxl];
    const float ys = (float)(ho - 1 + ki) + dy;
    const float xs = (float)(px - 1 + kj) + dx;
    const float y0f = floorf(ys), x0f = floorf(xs);
    const int y0 = (int)y0f, x0 = (int)x0f;
    const int y1 = y0 + 1, x1 = x0 + 1;
    const float wy1 = ys - y0f, wx1 = xs - x0f;
    const float wy0 = 1.f - wy1, wx0 = 1.f - wx1;
    const bool vy0 = (unsigned)y0 < (unsigned)H_, vy1 = (unsigned)y1 < (unsigned)H_;
    const bool vx0 = (unsigned)x0 < (unsigned)W_, vx1 = (unsigned)x1 < (unsigned)W_;
    const float g00 = (vy0 && vx0) ? wy0 * wx0 : 0.f;
    const float g01 = (vy0 && vx1) ? wy0 * wx1 : 0.f;
    const float g10 = (vy1 && vx0) ? wy1 * wx0 : 0.f;
    const float g11 = (vy1 && vx1) ? wy1 * wx1 : 0.f;
    const int yc0 = min(max(y0, 0), H_ - 1), yc1 = min(max(y1, 0), H_ - 1);
    const int xc0 = min(max(x0, 0), W_ - 1), xc1 = min(max(x1, 0), W_ - 1);
    const int rr0 = yc0 - ho0 + 2, rr1 = yc1 - ho0 + 2;
    const bool in = ((unsigned)rr0 < 6u) & ((unsigned)rr1 < 6u);
    const unsigned short* wt2 = w2b + t * 4096;

    if (__builtin_expect(__any(!in), 0)) {
      // slow path (|dy| >= ~1): gather from CHW x directly; correct for any offset
      #pragma unroll 1
      for (int ss = 0; ss < 4; ++ss) {
        short8 bf;
        #pragma unroll
        for (int i = 0; i < 8; ++i) {
          const float* img = xb + (size_t)((2 * ss + laneh) * 8 + i) * HW_;
          float v = g00 * img[yc0 * W_ + xc0] + g01 * img[yc0 * W_ + xc1]
                  + g10 * img[yc1 * W_ + xc0] + g11 * img[yc1 * W_ + xc1];
          bf[i] = (short)f2bfh(v);
        }
        const short8 a0 = *(const short8*)&wt2[(ss * 64 + lane) * 8];
        const short8 a1 = *(const short8*)&wt2[((4 + ss) * 64 + lane) * 8];
        acc0 = __builtin_amdgcn_mfma_f32_32x32x16_bf16(a0, bf, acc0, 0, 0, 0);
        acc1 = __builtin_amdgcn_mfma_f32_32x32x16_bf16(a1, bf, acc1, 0, 0, 0);
      }
      continue;
    }

    const int u00 = ((rr0 << 7) + xc0) << 4, u01 = ((rr0 << 7) + xc1) << 4;
    const int u10 = ((rr1 << 7) + xc0) << 4, u11 = ((rr1 << 7) + xc1) << 4;

    // hoist the 16 corner b128 reads for this tap
    short8 c00[4], c01[4], c10[4], c11[4];
    #pragma unroll
    for (int ss = 0; ss < 4; ++ss) {
      const char* pb = smem + (2 * ss + laneh) * PSTRIDE_B;
      c00[ss] = *(const short8*)(pb + u00);
      c01[ss] = *(const short8*)(pb + u01);
      c10[ss] = *(const short8*)(pb + u10);
      c11[ss] = *(const short8*)(pb + u11);
    }

    #pragma unroll
    for (int ss = 0; ss < 4; ++ss) {
      short8 bf;
      #pragma unroll
      for (int d = 0; d < 4; ++d) {               // packed 2-wide f32 blend per dword
        const unsigned w00 = ((const unsigned*)&c00[ss])[d];
        const unsigned w01 = ((const unsigned*)&c01[ss])[d];
        const unsigned w10 = ((const unsigned*)&c10[ss])[d];
        const unsigned w11 = ((const unsigned*)&c11[ss])[d];
        float2v p00, p01, p10, p11;
        p00.x = uaf(w00 << 16); p00.y = uaf(w00 & 0xFFFF0000u);
        p01.x = uaf(w01 << 16); p01.y = uaf(w01 & 0xFFFF0000u);
        p10.x = uaf(w10 << 16); p10.y = uaf(w10 & 0xFFFF0000u);
        p11.x = uaf(w11 << 16); p11.y = uaf(w11 & 0xFFFF0000u);
        float2v v = p00 * g00 + p01 * g01 + p10 * g10 + p11 * g11;
        ((unsigned*)&bf)[d] = (unsigned)f2bfh(v.x) | ((unsigned)f2bfh(v.y) << 16);
      }
      const short8 a0 = *(const short8*)&wt2[(ss * 64 + lane) * 8];
      const short8 a1 = *(const short8*)&wt2[((4 + ss) * 64 + lane) * 8];
      acc0 = __builtin_amdgcn_mfma_f32_32x32x16_bf16(a0, bf, acc0, 0, 0, 0);
      acc1 = __builtin_amdgcn_mfma_f32_32x32x16_bf16(a1, bf, acc1, 0, 0, 0);
    }
  }

  // ---- epilogue: direct stores (wave owns full M=64 of its strip) ----
  #pragma unroll
  for (int reg = 0; reg < 16; ++reg) {
    const int row = (reg & 3) + 8 * (reg >> 2) + 4 * laneh;
    out[((b * 64 + row)      * H_ + ho) * W_ + px] = acc0[reg] + bias[row];
    out[((b * 64 + 32 + row) * H_ + ho) * W_ + px] = acc1[reg] + bias[32 + row];
  }
}

extern "C" void kernel_launch(void* const* d_in, const int* in_sizes, int n_in,
                              void* d_out, int out_size, void* d_ws, size_t ws_size,
                              hipStream_t stream) {
  const float* x    = (const float*)d_in[0];
  const float* wt   = (const float*)d_in[1];
  const float* bias = (const float*)d_in[2];
  const float* ow   = (const float*)d_in[3];
  const float* ob   = (const float*)d_in[4];
  float* out = (float*)d_out;

  unsigned short* ws_u = (unsigned short*)d_ws;
  unsigned short* w2b  = ws_u;
  unsigned short* w2a  = ws_u + W2B_ELEMS;

  const int pack_blocks = (W2B_ELEMS + W2A_ELEMS + 255) / 256;   // 216
  pack_w_only<<<pack_blocks, 256, 0, stream>>>(wt, ow, ws_u);

  deform_fused8<<<B_ * (H_ / 2), 512, 0, stream>>>(x, bias, ob, w2b, w2a, out);
}

// Round 14
// 36.900 us; speedup vs baseline: 1.1348x; 1.1348x over previous
//
#include <hip/hip_runtime.h>
#include <hip/hip_bf16.h>

#define B_ 4
#define C_ 64
#define H_ 128
#define W_ 128
#define HW_ (H_ * W_)
#define OCH_ 18

typedef __attribute__((ext_vector_type(2)))  _Float16 half2v;
typedef __attribute__((ext_vector_type(8)))  _Float16 half8;
typedef __attribute__((ext_vector_type(16))) float    f32x16;

// ws layout (elements of unsigned short, now FP16 bits):
//   [0, W2B_ELEMS)              w2b: main weights, A-frag order (f16)
//   [W2B_ELEMS, +W2A_ELEMS)     w2a: offset-conv weights, A-frag order (f16)
#define W2B_ELEMS (9 * 2 * 4 * 64 * 8)   // 36864
#define W2A_ELEMS (36 * 64 * 8)          // 18432

// LDS: window 8 planes(8ch) x 6 rows x 128 cols x 16B (+pad), then per-wave offset
// exchange region: 8 waves x 18 oc x 32 px floats.
#define PSTRIDE_B (6 * 128 * 16 + 16)    // 12304
#define WIN_BYTES (8 * PSTRIDE_B)        // 98432
#define OFFL_OFS  WIN_BYTES
#define OFFW_B    (OCH_ * 32 * 4)        // 2304 per wave
#define SMEM_BYTES (WIN_BYTES + 8 * OFFW_B)   // 116864

__device__ __forceinline__ unsigned short f2h(float f) {   // f32 -> f16 bits (RNE)
  _Float16 h = (_Float16)f;
  return *reinterpret_cast<unsigned short*>(&h);
}
__device__ __forceinline__ half2v pkrtz(float a, float b) {  // cvt_pkrtz, bit-cast
  auto p = __builtin_amdgcn_cvt_pkrtz(a, b);
  return *reinterpret_cast<half2v*>(&p);
}
// bijective XCD swizzle for 256-block grid; consecutive ho0 stay on one XCD
__device__ __forceinline__ int swz256(int x) { return (x & 7) * 32 + (x >> 3); }
// Bank-swizzled byte offset of element (row,col) in a window plane (16B elems).
// Low-2 col bits XOR'd with col bits 3..4: consecutive-lane 64B-stride writes
// (stage) spread over all 8 bank-quads; bijective within each 4-col group.
__device__ __forceinline__ int SWU(int row, int col) {
  return (((row << 7) + (col & ~3) + ((col & 3) ^ ((col >> 3) & 3))) << 4);
}

// ---------------- weight pack (f16) ----------------
__global__ __launch_bounds__(256) void pack_w_only(
    const float* __restrict__ wmain, const float* __restrict__ offw,
    unsigned short* __restrict__ ws_u) {
  int idx = blockIdx.x * 256 + threadIdx.x;
  if (idx < W2B_ELEMS) {
    int i = idx & 7, lane = (idx >> 3) & 63, s = (idx >> 9) & 3;
    int mq = (idx >> 11) & 1, t = idx >> 12;
    int o = mq * 32 + (lane & 31);
    int c = 16 * s + (lane >> 5) * 8 + i;
    ws_u[idx] = f2h(wmain[(o * 64 + c) * 9 + t]);
  } else if (idx < W2B_ELEMS + W2A_ELEMS) {
    int j = idx - W2B_ELEMS;
    int i = j & 7, lane = (j >> 3) & 63, s = j >> 9;   // s 0..35
    int kg = 16 * s + (lane >> 5) * 8 + i;
    int t = kg >> 6, c = kg & 63, oc = lane & 31;
    ws_u[idx] = (oc < OCH_) ? f2h(offw[(oc * 64 + c) * 9 + t]) : (unsigned short)0;
  }
}

// ---------------- branchless fast tap (template T) ----------------
template<int T>
__device__ __forceinline__ void tap_fast(
    const float* __restrict__ offl, int pxl, int ho, int ho0, int px,
    int lane, int laneh, const char* __restrict__ smem,
    const unsigned short* __restrict__ w2b,
    f32x16& acc0, f32x16& acc1, unsigned& fm) {
  constexpr int KI = T / 3, KJ = T - 3 * (T / 3);
  const float dy = offl[(2 * T) * 32 + pxl];
  const float dx = offl[(2 * T + 1) * 32 + pxl];
  const float ys = (float)(ho - 1 + KI) + dy;
  const float xs = (float)(px - 1 + KJ) + dx;
  const float y0f = floorf(ys), x0f = floorf(xs);
  const int y0 = (int)y0f, x0 = (int)x0f;
  const int y1 = y0 + 1, x1 = x0 + 1;
  const float wy1 = ys - y0f, wx1 = xs - x0f;
  const float wy0 = 1.f - wy1, wx0 = 1.f - wx1;
  const bool vy0 = (unsigned)y0 < (unsigned)H_, vy1 = (unsigned)y1 < (unsigned)H_;
  const bool vx0 = (unsigned)x0 < (unsigned)W_, vx1 = (unsigned)x1 < (unsigned)W_;
  const float g00 = (vy0 && vx0) ? wy0 * wx0 : 0.f;
  const float g01 = (vy0 && vx1) ? wy0 * wx1 : 0.f;
  const float g10 = (vy1 && vx0) ? wy1 * wx0 : 0.f;
  const float g11 = (vy1 && vx1) ? wy1 * wx1 : 0.f;
  const int yc0 = min(max(y0, 0), H_ - 1), yc1 = min(max(y1, 0), H_ - 1);
  const int xc0 = min(max(x0, 0), W_ - 1), xc1 = min(max(x1, 0), W_ - 1);
  const int rr0 = yc0 - ho0 + 2, rr1 = yc1 - ho0 + 2;
  const bool wr0 = (unsigned)rr0 < 6u, wr1 = (unsigned)rr1 < 6u;
  // zero the weights of out-of-window corners (per-lane); fixup adds them later
  const float gg00 = wr0 ? g00 : 0.f, gg01 = wr0 ? g01 : 0.f;
  const float gg10 = wr1 ? g10 : 0.f, gg11 = wr1 ? g11 : 0.f;
  if (__any((!wr0 & (vy0 & (vx0 | vx1))) | (!wr1 & (vy1 & (vx0 | vx1)))))
    fm |= (1u << T);
  const int cr0 = min(max(rr0, 0), 5), cr1 = min(max(rr1, 0), 5);
  const int u00 = SWU(cr0, xc0), u01 = SWU(cr0, xc1);
  const int u10 = SWU(cr1, xc0), u11 = SWU(cr1, xc1);
  half2v G00; G00.x = G00.y = (_Float16)gg00;
  half2v G01; G01.x = G01.y = (_Float16)gg01;
  half2v G10; G10.x = G10.y = (_Float16)gg10;
  half2v G11; G11.x = G11.y = (_Float16)gg11;
  const unsigned short* wt2 = w2b + T * 4096;

  #pragma unroll
  for (int ss = 0; ss < 4; ++ss) {
    const char* pb = smem + (2 * ss + laneh) * PSTRIDE_B;
    const half8 c00 = *(const half8*)(pb + u00);
    const half8 c01 = *(const half8*)(pb + u01);
    const half8 c10 = *(const half8*)(pb + u10);
    const half8 c11 = *(const half8*)(pb + u11);
    const half2v* p00 = (const half2v*)&c00;
    const half2v* p01 = (const half2v*)&c01;
    const half2v* p10 = (const half2v*)&c10;
    const half2v* p11 = (const half2v*)&c11;
    union { half8 v; half2v h[4]; } bf;
    #pragma unroll
    for (int d = 0; d < 4; ++d)    // 4x v_pk ops per dword, no unpack/repack
      bf.h[d] = p00[d] * G00 + p01[d] * G01 + p10[d] * G10 + p11[d] * G11;
    const half8 a0 = *(const half8*)&wt2[(ss * 64 + lane) * 8];
    const half8 a1 = *(const half8*)&wt2[((4 + ss) * 64 + lane) * 8];
    acc0 = __builtin_amdgcn_mfma_f32_32x32x16_f16(a0, bf.v, acc0, 0, 0, 0);
    acc1 = __builtin_amdgcn_mfma_f32_32x32x16_f16(a1, bf.v, acc1, 0, 0, 0);
  }
}

// ---------------- fused kernel v9: f16 window, swizzled stage, branchless taps ---------
// block=(b, ho0=2*rb): 256 blocks x 512 threads (8 waves).
// wave = (r_off = wave>>2, pair = wave&3): output row ho0+r_off, px strip pair*32..+32.
__global__ __launch_bounds__(512, 2) void deform_fused9(
    const float* __restrict__ x, const float* __restrict__ bias,
    const float* __restrict__ ob, const unsigned short* __restrict__ w2b,
    const unsigned short* __restrict__ w2a, float* __restrict__ out) {
  const int blk = swz256(blockIdx.x);
  const int ho0 = (blk & 63) * 2;
  const int b   = blk >> 6;
  const int tid = threadIdx.x;
  const int lane = tid & 63;
  const int wave = tid >> 6;
  const int r_off = wave >> 2;
  const int pair  = wave & 3;
  const int ho = ho0 + r_off;
  const int pxl = lane & 31;
  const int px = pair * 32 + pxl;
  const int laneh = lane >> 5;

  __shared__ __align__(16) char smem[SMEM_BYTES];

  // ---- stage: rows ho0-2..ho0+3 (clamped), reg transpose, swizzled b128 writes ----
  const float* xb = x + (size_t)b * C_ * HW_;
  #pragma unroll
  for (int it = 0; it < 3; ++it) {
    const int u = tid + it * 512;          // 1536 units: [row(6)][p(8)][col4(32)]
    const int row  = u >> 8;
    const int p    = (u >> 5) & 7;
    const int col4 = u & 31;
    const int srow = min(H_ - 1, max(0, ho0 - 2 + row));
    const float* bp = xb + (size_t)(p * 8) * HW_ + srow * W_ + col4 * 4;
    float4 f[8];
    #pragma unroll
    for (int i = 0; i < 8; ++i) f[i] = *(const float4*)(bp + (size_t)i * HW_);
    char* outb = smem + p * PSTRIDE_B;
    #pragma unroll
    for (int j = 0; j < 4; ++j) {
      union { half8 v; half2v h[4]; } o;
      #pragma unroll
      for (int k = 0; k < 4; ++k)
        o.h[k] = pkrtz(reinterpret_cast<const float*>(&f[2 * k])[j],
                       reinterpret_cast<const float*>(&f[2 * k + 1])[j]);
      *(half8*)(outb + SWU(row, col4 * 4 + j)) = o.v;
    }
  }
  __syncthreads();                         // the only barrier

  // ---- phase 1: offset conv, rolled (18 x dual-chain), f16 MFMA ----
  f32x16 pacc_a, pacc_b;
  #pragma unroll
  for (int r = 0; r < 16; ++r) { pacc_a[r] = 0.f; pacc_b[r] = 0.f; }

  #pragma unroll 1
  for (int sq = 0; sq < 18; ++sq) {
    #pragma unroll
    for (int h = 0; h < 2; ++h) {
      const int s = 2 * sq + h;
      const int t = s >> 2;
      const int ki = (t >= 6) ? 2 : ((t >= 3) ? 1 : 0);
      const int kj = t - 3 * ki;
      const int row = ho - 1 + ki;
      const int col = px - 1 + kj;
      half8 bfr = {0, 0, 0, 0, 0, 0, 0, 0};
      if (((unsigned)row < (unsigned)H_) && ((unsigned)col < (unsigned)W_))
        bfr = *(const half8*)(smem + ((s & 3) * 2 + laneh) * PSTRIDE_B
                              + SWU(ki + 1 + r_off, col));
      const half8 afr = *(const half8*)&w2a[((size_t)s * 64 + lane) * 8];
      if (h)
        pacc_b = __builtin_amdgcn_mfma_f32_32x32x16_f16(afr, bfr, pacc_b, 0, 0, 0);
      else
        pacc_a = __builtin_amdgcn_mfma_f32_32x32x16_f16(afr, bfr, pacc_a, 0, 0, 0);
    }
  }

  // ---- write offsets (+bias) to wave-private LDS region; no barrier needed ----
  float* offl = (float*)(smem + OFFL_OFS + wave * OFFW_B);
  #pragma unroll
  for (int reg = 0; reg < 16; ++reg) {
    const int oc = (reg & 3) + 8 * (reg >> 2) + 4 * laneh;
    if (oc < OCH_) offl[oc * 32 + pxl] = pacc_a[reg] + pacc_b[reg] + ob[oc];
  }

  // ---- phase 2: 9 branchless taps (unrolled, free to pipeline) ----
  f32x16 acc0, acc1;
  #pragma unroll
  for (int r = 0; r < 16; ++r) { acc0[r] = 0.f; acc1[r] = 0.f; }
  unsigned fm = 0;

  tap_fast<0>(offl, pxl, ho, ho0, px, lane, laneh, smem, w2b, acc0, acc1, fm);
  tap_fast<1>(offl, pxl, ho, ho0, px, lane, laneh, smem, w2b, acc0, acc1, fm);
  tap_fast<2>(offl, pxl, ho, ho0, px, lane, laneh, smem, w2b, acc0, acc1, fm);
  tap_fast<3>(offl, pxl, ho, ho0, px, lane, laneh, smem, w2b, acc0, acc1, fm);
  tap_fast<4>(offl, pxl, ho, ho0, px, lane, laneh, smem, w2b, acc0, acc1, fm);
  tap_fast<5>(offl, pxl, ho, ho0, px, lane, laneh, smem, w2b, acc0, acc1, fm);
  tap_fast<6>(offl, pxl, ho, ho0, px, lane, laneh, smem, w2b, acc0, acc1, fm);
  tap_fast<7>(offl, pxl, ho, ho0, px, lane, laneh, smem, w2b, acc0, acc1, fm);
  tap_fast<8>(offl, pxl, ho, ho0, px, lane, laneh, smem, w2b, acc0, acc1, fm);

  // ---- rare fixup: add contributions of out-of-window corners from global ----
  if (__builtin_expect(fm != 0, 0)) {
    #pragma unroll 1
    for (int t = 0; t < 9; ++t) {
      if (!((fm >> t) & 1)) continue;
      const int ki = (t >= 6) ? 2 : ((t >= 3) ? 1 : 0);
      const int kj = t - 3 * ki;
      const float dy = offl[(2 * t) * 32 + pxl];
      const float dx = offl[(2 * t + 1) * 32 + pxl];
      const float ys = (float)(ho - 1 + ki) + dy;
      const float xs = (float)(px - 1 + kj) + dx;
      const float y0f = floorf(ys), x0f = floorf(xs);
      const int y0 = (int)y0f, x0 = (int)x0f;
      const int y1 = y0 + 1, x1 = x0 + 1;
      const float wy1 = ys - y0f, wx1 = xs - x0f;
      const float wy0 = 1.f - wy1, wx0 = 1.f - wx1;
      const bool vy0 = (unsigned)y0 < (unsigned)H_, vy1 = (unsigned)y1 < (unsigned)H_;
      const bool vx0 = (unsigned)x0 < (unsigned)W_, vx1 = (unsigned)x1 < (unsigned)W_;
      float g00 = (vy0 && vx0) ? wy0 * wx0 : 0.f;
      float g01 = (vy0 && vx1) ? wy0 * wx1 : 0.f;
      float g10 = (vy1 && vx0) ? wy1 * wx0 : 0.f;
      float g11 = (vy1 && vx1) ? wy1 * wx1 : 0.f;
      const int yc0 = min(max(y0, 0), H_ - 1), yc1 = min(max(y1, 0), H_ - 1);
      const int xc0 = min(max(x0, 0), W_ - 1), xc1 = min(max(x1, 0), W_ - 1);
      const bool wr0 = (unsigned)(yc0 - ho0 + 2) < 6u;
      const bool wr1 = (unsigned)(yc1 - ho0 + 2) < 6u;
      // only the corners that were zeroed in the fast path
      g00 = wr0 ? 0.f : g00; g01 = wr0 ? 0.f : g01;
      g10 = wr1 ? 0.f : g10; g11 = wr1 ? 0.f : g11;
      const unsigned short* wt2 = w2b + t * 4096;
      #pragma unroll 1
      for (int ss = 0; ss < 4; ++ss) {
        union { half8 v; _Float16 e[8]; } bf;
        #pragma unroll
        for (int i = 0; i < 8; ++i) {
          const float* img = xb + (size_t)((2 * ss + laneh) * 8 + i) * HW_;
          float v = g00 * img[yc0 * W_ + xc0] + g01 * img[yc0 * W_ + xc1]
                  + g10 * img[yc1 * W_ + xc0] + g11 * img[yc1 * W_ + xc1];
          bf.e[i] = (_Float16)v;
        }
        const half8 a0 = *(const half8*)&wt2[(ss * 64 + lane) * 8];
        const half8 a1 = *(const half8*)&wt2[((4 + ss) * 64 + lane) * 8];
        acc0 = __builtin_amdgcn_mfma_f32_32x32x16_f16(a0, bf.v, acc0, 0, 0, 0);
        acc1 = __builtin_amdgcn_mfma_f32_32x32x16_f16(a1, bf.v, acc1, 0, 0, 0);
      }
    }
  }

  // ---- epilogue: direct stores (wave owns full M=64 of its strip) ----
  #pragma unroll
  for (int reg = 0; reg < 16; ++reg) {
    const int row = (reg & 3) + 8 * (reg >> 2) + 4 * laneh;
    out[((b * 64 + row)      * H_ + ho) * W_ + px] = acc0[reg] + bias[row];
    out[((b * 64 + 32 + row) * H_ + ho) * W_ + px] = acc1[reg] + bias[32 + row];
  }
}

extern "C" void kernel_launch(void* const* d_in, const int* in_sizes, int n_in,
                              void* d_out, int out_size, void* d_ws, size_t ws_size,
                              hipStream_t stream) {
  const float* x    = (const float*)d_in[0];
  const float* wt   = (const float*)d_in[1];
  const float* bias = (const float*)d_in[2];
  const float* ow   = (const float*)d_in[3];
  const float* ob   = (const float*)d_in[4];
  float* out = (float*)d_out;

  unsigned short* ws_u = (unsigned short*)d_ws;
  unsigned short* w2b  = ws_u;
  unsigned short* w2a  = ws_u + W2B_ELEMS;

  const int pack_blocks = (W2B_ELEMS + W2A_ELEMS + 255) / 256;   // 216
  pack_w_only<<<pack_blocks, 256, 0, stream>>>(wt, ow, ws_u);

  deform_fused9<<<B_ * (H_ / 2), 512, 0, stream>>>(x, bias, ob, w2b, w2a, out);
}